// Round 4
// baseline (750.621 us; speedup 1.0000x reference)
//
#include <hip/hip_runtime.h>

#define DIM 1536
#define NH 12
#define HD 128
#define S_LEN 5400
#define SPAD 5440      // 85*64  (kv tiles)
#define MPAD 5504      // 43*128 (GEMM M tiles) = 86*64 (flash q tiles)
#define NQKV 4608
#define EPS_NORM 1e-6f

typedef __bf16 bf16_t;
typedef __bf16 bf16x8 __attribute__((ext_vector_type(8)));
typedef __bf16 bf16x4 __attribute__((ext_vector_type(4)));
typedef float  f32x4  __attribute__((ext_vector_type(4)));

// async global->LDS, 16B per lane; LDS dest is wave-uniform base + lane*16
#define GLOAD_LDS16(gp, lp) __builtin_amdgcn_global_load_lds( \
    (__attribute__((address_space(1))) void*)(void*)(gp),     \
    (__attribute__((address_space(3))) void*)(lp), 16, 0, 0)

// ---------------- conversion kernels ----------------

__global__ __launch_bounds__(256) void cvt_x_kernel(const float* __restrict__ x,
                                                    bf16_t* __restrict__ xb) {
  size_t base = ((size_t)blockIdx.x * 256 + threadIdx.x) * 4;
  if (base >= (size_t)MPAD * DIM) return;
  size_t row = base / DIM;
  float4 v = make_float4(0.f, 0.f, 0.f, 0.f);
  if (row < S_LEN) v = *(const float4*)&x[base];
  bf16x4 o; o[0] = (__bf16)v.x; o[1] = (__bf16)v.y; o[2] = (__bf16)v.z; o[3] = (__bf16)v.w;
  *(bf16x4*)&xb[base] = o;
}

__global__ __launch_bounds__(256) void cvt_wqkv_kernel(const float* __restrict__ qw,
                                                       const float* __restrict__ kw,
                                                       const float* __restrict__ vw,
                                                       bf16_t* __restrict__ wb) {
  size_t base = ((size_t)blockIdx.x * 256 + threadIdx.x) * 4;
  if (base >= (size_t)NQKV * DIM) return;
  int row = (int)(base / DIM);
  int col = (int)(base - (size_t)row * DIM);
  const float* src; int rr = row;
  if (rr >= 3072)      { src = vw; rr -= 3072; }
  else if (rr >= 1536) { src = kw; rr -= 1536; }
  else                 { src = qw; }
  float4 v = *(const float4*)&src[(size_t)rr * DIM + col];
  bf16x4 o; o[0] = (__bf16)v.x; o[1] = (__bf16)v.y; o[2] = (__bf16)v.z; o[3] = (__bf16)v.w;
  *(bf16x4*)&wb[base] = o;
}

__global__ __launch_bounds__(256) void cvt_wo_kernel(const float* __restrict__ w,
                                                     bf16_t* __restrict__ wb) {
  size_t base = ((size_t)blockIdx.x * 256 + threadIdx.x) * 4;
  if (base >= (size_t)DIM * DIM) return;
  float4 v = *(const float4*)&w[base];
  bf16x4 o; o[0] = (__bf16)v.x; o[1] = (__bf16)v.y; o[2] = (__bf16)v.z; o[3] = (__bf16)v.w;
  *(bf16x4*)&wb[base] = o;
}

// ---------------- GEMM: C[M,N] = A[M,K] @ B[N,K]^T + bias ----------------

template<bool OUT_BF16>
__global__ __launch_bounds__(256) void gemm_bt_kernel(
    const bf16_t* __restrict__ A, const bf16_t* __restrict__ B, void* __restrict__ C,
    const float* __restrict__ bias0, const float* __restrict__ bias1,
    const float* __restrict__ bias2, int M, int N, int K, int Mvalid) {
  __shared__ bf16_t As[128 * 32];
  __shared__ bf16_t Bs[128 * 32];
  int tid = threadIdx.x;
  int lane = tid & 63, wave = tid >> 6, quad = lane >> 4, l16 = lane & 15;
  int m0 = blockIdx.y * 128, n0 = blockIdx.x * 128;
  int wm = (wave >> 1) * 64, wn = (wave & 1) * 64;
  const bf16_t* Ab = A + (size_t)m0 * K;
  const bf16_t* Bb = B + (size_t)n0 * K;
  f32x4 acc[4][4] = {};
  for (int kt = 0; kt < K; kt += 32) {
    __syncthreads();
#pragma unroll
    for (int i = 0; i < 2; i++) {
      int eo = (i * 256 + tid) * 8;       // 128x32 tile, 8 bf16 per lane-slot
      int row = eo >> 5, col = eo & 31;
      GLOAD_LDS16(Ab + (size_t)row * K + kt + col, &As[eo]);
      GLOAD_LDS16(Bb + (size_t)row * K + kt + col, &Bs[eo]);
    }
    __syncthreads();
    bf16x8 af[4], bfr[4];
#pragma unroll
    for (int i = 0; i < 4; i++)
      af[i] = *(const bf16x8*)&As[(wm + i * 16 + l16) * 32 + quad * 8];
#pragma unroll
    for (int j = 0; j < 4; j++)
      bfr[j] = *(const bf16x8*)&Bs[(wn + j * 16 + l16) * 32 + quad * 8];
#pragma unroll
    for (int i = 0; i < 4; i++)
#pragma unroll
      for (int j = 0; j < 4; j++)
        acc[i][j] = __builtin_amdgcn_mfma_f32_16x16x32_bf16(af[i], bfr[j], acc[i][j], 0, 0, 0);
  }
  // epilogue: C/D layout col=lane&15, row=quad*4+reg  [m89-verified]
#pragma unroll
  for (int j = 0; j < 4; j++) {
    int n = n0 + wn + j * 16 + l16;
    float bias = (n < 1536) ? bias0[n] : (n < 3072) ? bias1[n - 1536] : bias2[n - 3072];
#pragma unroll
    for (int i = 0; i < 4; i++) {
#pragma unroll
      for (int r = 0; r < 4; r++) {
        int m = m0 + wm + i * 16 + quad * 4 + r;
        float v = acc[i][j][r] + bias;
        if (OUT_BF16) {
          ((bf16_t*)C)[(size_t)m * N + n] = (__bf16)v;
        } else {
          if (m < Mvalid) ((float*)C)[(size_t)m * N + n] = v;
        }
      }
    }
  }
}

// ---------------- RMSNorm + RoPE for q,k ----------------
// q additionally pre-scaled by 1/sqrt(HD) so flash logits need no scale.

__global__ __launch_bounds__(256) void rope_qk_kernel(
    const bf16_t* __restrict__ qkv, const float* __restrict__ nqw,
    const float* __restrict__ nkw, const float* __restrict__ fcos,
    const float* __restrict__ fsin, bf16_t* __restrict__ qout,
    bf16_t* __restrict__ kout) {
  int s = blockIdx.x;              // 0..MPAD-1
  int tid = threadIdx.x;
  bool valid = s < S_LEN;
  int f = s / 900, hh = (s / 30) % 30, ww = s % 30;
  __shared__ float red[4];
  for (int which = 0; which < 2; which++) {
    const bf16_t* src = qkv + (size_t)s * NQKV + which * DIM;
    const float* nw = which ? nkw : nqw;
    bf16_t* dst = (which ? kout : qout) + (size_t)s * DIM;
    float osc = which ? 1.0f : 0.08838834764831845f;   // 1/sqrt(128) folded into q
    float v[6]; float ss = 0.f;
#pragma unroll
    for (int i = 0; i < 6; i++) {
      v[i] = valid ? (float)src[tid * 6 + i] : 0.f;
      ss += v[i] * v[i];
    }
#pragma unroll
    for (int off = 32; off >= 1; off >>= 1) ss += __shfl_down(ss, off);
    if ((tid & 63) == 0) red[tid >> 6] = ss;
    __syncthreads();
    float tot = red[0] + red[1] + red[2] + red[3];
    float rn = rsqrtf(tot * (1.f / DIM) + EPS_NORM);
    __syncthreads();   // protect red[] before next `which` iteration
#pragma unroll
    for (int i = 0; i < 3; i++) {
      int e0 = tid * 6 + 2 * i;
      int p = e0 >> 1;             // pair index; cc = p&63
      int cc = p & 63;
      int pos = (cc < 22) ? f : (cc < 43) ? hh : ww;  // split [22,21,21]
      float c = fcos[pos * 64 + cc], sn = fsin[pos * 64 + cc];
      float xr = v[2 * i] * rn * nw[e0];
      float xi = v[2 * i + 1] * rn * nw[e0 + 1];
      dst[e0]     = (__bf16)((xr * c - xi * sn) * osc);
      dst[e0 + 1] = (__bf16)((xr * sn + xi * c) * osc);
    }
  }
}

// ---------------- V transpose: qkv v-part -> vt[h][d][s] ----------------

__global__ __launch_bounds__(256) void v_transpose_kernel(const bf16_t* __restrict__ qkv,
                                                          bf16_t* __restrict__ vt) {
  __shared__ bf16_t tile[64][136];   // +8 pad
  int h = blockIdx.y, s0 = blockIdx.x * 64, tid = threadIdx.x;
#pragma unroll
  for (int it = 0; it < 4; it++) {
    int eo = (it * 256 + tid) * 8;   // 64x128 elements
    int row = eo >> 7, col = eo & 127;
    int s = s0 + row;
    bf16x8 val = {};
    if (s < S_LEN) val = *(const bf16x8*)&qkv[(size_t)s * NQKV + 3072 + h * HD + col];
    *(bf16x8*)&tile[row][col] = val;
  }
  __syncthreads();
  int d = tid & 127, j0 = (tid >> 7) * 32;
  bf16x8 outv[4];
#pragma unroll
  for (int b = 0; b < 4; b++)
#pragma unroll
    for (int j = 0; j < 8; j++) outv[b][j] = tile[j0 + b * 8 + j][d];
  size_t base = ((size_t)h * HD + d) * SPAD + s0 + j0;
#pragma unroll
  for (int b = 0; b < 4; b++) *(bf16x8*)&vt[base + b * 8] = outv[b];
}

// ---------------- flash attention (S^T = K Q^T orientation) ----------------
// grid (86 q-tiles of 64, 12 heads) = 1032 blocks -> ~4 blocks/CU.
// 256 threads = 4 waves; each wave owns 16 q rows.
// LDS: K-tile (16 KB) + V-tile (16 KB) = 32 KB; Q frags in registers.
// P C-layout -> B-layout via cross-lane shuffles (no LDS round-trip).

__global__ __launch_bounds__(256, 4) void flash_attn_kernel(
    const bf16_t* __restrict__ q, const bf16_t* __restrict__ k,
    const bf16_t* __restrict__ vt, bf16_t* __restrict__ o) {
  __shared__ bf16_t smem[16384];     // 32 KB: Ks [0,8192), Vs [8192,16384); reused as Ot
  bf16_t* Ks = smem;
  bf16_t* Vs = smem + 8192;
  int h = blockIdx.y;
  int s0 = blockIdx.x * 64;
  int tid = threadIdx.x, w = tid >> 6, lane = tid & 63;
  int quad = lane >> 4, l16 = lane & 15;

  // ---- Q fragments straight from global (loop-invariant, 85x reuse)
  // B-frag: lane l16 = q row, k = ks*32 + quad*8 + j
  bf16x8 bq[4];
#pragma unroll
  for (int ks = 0; ks < 4; ks++) {
    int qrow = s0 + w * 16 + l16;
    bq[ks] = *(const bf16x8*)&q[(size_t)qrow * DIM + h * HD + ks * 32 + quad * 8];
  }

  float m_i = -1e30f, l_i = 0.f;
  f32x4 oacc[8] = {};
  int sA = (quad & 1) * 32 + l16;      // shuffle sources: quads (quad&1)*2, +1
  int sB = sA + 16;
  bool selhi = quad >= 2;              // block select: nsrc = 2ks + (quad>>1)

  for (int kt = 0; kt < SPAD; kt += 64) {
    __syncthreads();
    // stage K tile 64x128 (swizzled: chunk c at slot pc, c=(pc&8)|((pc&7)^(row&7)))
#pragma unroll
    for (int it = 0; it < 4; it++) {
      int slot = it * 256 + tid;
      int row = slot >> 4, pc = slot & 15;
      int c = (pc & 8) | ((pc & 7) ^ (row & 7));
      GLOAD_LDS16(k + (size_t)(kt + row) * DIM + h * HD + c * 8, &Ks[slot * 8]);
    }
    // stage V^T tile 128x64 (swizzled: c = pc ^ (d&7))
#pragma unroll
    for (int it = 0; it < 4; it++) {
      int slot = it * 256 + tid;
      int d = slot >> 3, pc = slot & 7;
      int c = pc ^ (d & 7);
      GLOAD_LDS16(vt + ((size_t)h * HD + d) * SPAD + kt + c * 8, &Vs[slot * 8]);
    }
    __syncthreads();

    // ---- S^T = K Q^T : D[kv=quad*4+r (+16ns)][q=l16]
    f32x4 sacc[4] = {};
#pragma unroll
    for (int ns = 0; ns < 4; ns++) {
      bf16x8 ak[4];
#pragma unroll
      for (int ks = 0; ks < 4; ks++) {
        int row = ns * 16 + l16;
        int ch = ks * 4 + quad;
        int pc = (ch & 8) | ((ch & 7) ^ (l16 & 7));
        ak[ks] = *(const bf16x8*)&Ks[row * 128 + pc * 8];
      }
#pragma unroll
      for (int ks = 0; ks < 4; ks++)
        sacc[ns] = __builtin_amdgcn_mfma_f32_16x16x32_bf16(ak[ks], bq[ks], sacc[ns], 0, 0, 0);
    }

    bool full = (kt + 64 <= S_LEN);
    // ---- online softmax, per q-col (= per lane, replicated over quads)
    unsigned int pkl[4], pkh[4];   // P packed bf16x4 (r=0..3) per ns
    if (!full) {
#pragma unroll
      for (int ns = 0; ns < 4; ns++)
#pragma unroll
        for (int r = 0; r < 4; r++)
          if (kt + ns * 16 + quad * 4 + r >= S_LEN) sacc[ns][r] = -1e30f;
    }
    float mx = -1e30f;
#pragma unroll
    for (int ns = 0; ns < 4; ns++)
#pragma unroll
      for (int r = 0; r < 4; r++) mx = fmaxf(mx, sacc[ns][r]);
    mx = fmaxf(mx, __shfl_xor(mx, 16));
    mx = fmaxf(mx, __shfl_xor(mx, 32));
    float mn = fmaxf(m_i, mx);
    float al = __expf(m_i - mn);
    m_i = mn;
    float rs = 0.f;
#pragma unroll
    for (int ns = 0; ns < 4; ns++) {
      bf16x4 pk;
#pragma unroll
      for (int r = 0; r < 4; r++) {
        float p = __expf(sacc[ns][r] - mn);
        rs += p;
        pk[r] = (__bf16)p;
      }
      union { bf16x4 v; unsigned int u[2]; } cv; cv.v = pk;
      pkl[ns] = cv.u[0]; pkh[ns] = cv.u[1];
    }
    rs += __shfl_xor(rs, 16);
    rs += __shfl_xor(rs, 32);
    l_i = l_i * al + rs;
#pragma unroll
    for (int dt = 0; dt < 8; dt++) oacc[dt] *= al;

    // ---- O^T += V^T P^T : D[d=quad*4+r (+16dt)][q=l16]
    // B-frag needs P[q=l16][kv=ks*32+quad*8+j]: lives in lane ((quad&1)*2+(j>=4))*16+l16,
    // block ns=2ks+(quad>>1), reg r=j&3. Shuffle both blocks, select by quad>>1.
#pragma unroll
    for (int ks = 0; ks < 2; ks++) {
      int b0 = __shfl((int)pkl[2 * ks], sA);
      int b1 = __shfl((int)pkh[2 * ks], sA);
      int b2 = __shfl((int)pkl[2 * ks], sB);
      int b3 = __shfl((int)pkh[2 * ks], sB);
      int c0 = __shfl((int)pkl[2 * ks + 1], sA);
      int c1 = __shfl((int)pkh[2 * ks + 1], sA);
      int c2 = __shfl((int)pkl[2 * ks + 1], sB);
      int c3 = __shfl((int)pkh[2 * ks + 1], sB);
      union { unsigned int u[4]; bf16x8 v; } cv;
      cv.u[0] = selhi ? (unsigned)c0 : (unsigned)b0;
      cv.u[1] = selhi ? (unsigned)c1 : (unsigned)b1;
      cv.u[2] = selhi ? (unsigned)c2 : (unsigned)b2;
      cv.u[3] = selhi ? (unsigned)c3 : (unsigned)b3;
      bf16x8 bp = cv.v;
#pragma unroll
      for (int dt = 0; dt < 8; dt++) {
        int ch = ks * 4 + quad;
        int pc = ch ^ (l16 & 7);
        bf16x8 av = *(const bf16x8*)&Vs[(dt * 16 + l16) * 64 + pc * 8];
        oacc[dt] = __builtin_amdgcn_mfma_f32_16x16x32_bf16(av, bp, oacc[dt], 0, 0, 0);
      }
    }
  }

  // ---- epilogue: O^T -> LDS (swizzled, transposed) -> coalesced global
  __syncthreads();                  // all waves done reading Ks/Vs
  bf16_t* Ot = smem;                // 64 q x 128 d
  {
    float inv = 1.f / l_i;
#pragma unroll
    for (int dt = 0; dt < 8; dt++) {
      bf16x4 v;
#pragma unroll
      for (int r = 0; r < 4; r++) v[r] = (__bf16)(oacc[dt][r] * inv);
      int qrow = w * 16 + l16;
      int c = dt * 2 + (quad >> 1);
      int pc = (c & 8) | ((c & 7) ^ (l16 & 7));   // qrow&7 == l16&7
      *(bf16x4*)&Ot[qrow * 128 + pc * 8 + (quad & 1) * 4] = v;
    }
  }
  __syncthreads();
#pragma unroll
  for (int i = 0; i < 4; i++) {
    int q_ = i * 16 + (tid >> 4);
    int cc = tid & 15;
    int pc = (cc & 8) | ((cc & 7) ^ (q_ & 7));
    bf16x8 val = *(const bf16x8*)&Ot[q_ * 128 + pc * 8];
    int s = s0 + q_;
    if (s < S_LEN) *(bf16x8*)&o[(size_t)s * DIM + h * HD + cc * 8] = val;
  }
}

// ---------------- launch ----------------

extern "C" void kernel_launch(void* const* d_in, const int* in_sizes, int n_in,
                              void* d_out, int out_size, void* d_ws, size_t ws_size,
                              hipStream_t stream) {
  const float* x    = (const float*)d_in[0];
  const float* q_w  = (const float*)d_in[1];
  const float* q_b  = (const float*)d_in[2];
  const float* k_w  = (const float*)d_in[3];
  const float* k_b  = (const float*)d_in[4];
  const float* v_w  = (const float*)d_in[5];
  const float* v_b  = (const float*)d_in[6];
  const float* o_w  = (const float*)d_in[7];
  const float* o_b  = (const float*)d_in[8];
  const float* nqw  = (const float*)d_in[9];
  const float* nkw  = (const float*)d_in[10];
  const float* fcos = (const float*)d_in[11];
  const float* fsin = (const float*)d_in[12];

  char* ws = (char*)d_ws;
  bf16_t* xb   = (bf16_t*)(ws + 0);
  bf16_t* wqkv = (bf16_t*)(ws + 16908288);
  bf16_t* wob  = (bf16_t*)(ws + 31064064);
  bf16_t* qkv  = (bf16_t*)(ws + 35782656);
  bf16_t* qb   = (bf16_t*)(ws + 86507520);
  bf16_t* kb   = (bf16_t*)(ws + 103415808);
  bf16_t* vtb  = (bf16_t*)(ws + 0);         // alias xb (dead after GEMM1)
  bf16_t* aob  = (bf16_t*)(ws + 35782656);  // alias qkv (dead after rope+transpose)

  cvt_x_kernel<<<(MPAD * DIM / 4 + 255) / 256, 256, 0, stream>>>(x, xb);
  cvt_wqkv_kernel<<<(NQKV * DIM / 4 + 255) / 256, 256, 0, stream>>>(q_w, k_w, v_w, wqkv);
  cvt_wo_kernel<<<(DIM * DIM / 4 + 255) / 256, 256, 0, stream>>>(o_w, wob);

  gemm_bt_kernel<true><<<dim3(NQKV / 128, MPAD / 128), 256, 0, stream>>>(
      xb, wqkv, qkv, q_b, k_b, v_b, MPAD, NQKV, DIM, MPAD);

  rope_qk_kernel<<<MPAD, 256, 0, stream>>>(qkv, nqw, nkw, fcos, fsin, qb, kb);
  v_transpose_kernel<<<dim3(SPAD / 64, NH), 256, 0, stream>>>(qkv, vtb);

  flash_attn_kernel<<<dim3(MPAD / 64, NH), 256, 0, stream>>>(qb, kb, vtb, aob);

  gemm_bt_kernel<false><<<dim3(DIM / 128, MPAD / 128), 256, 0, stream>>>(
      aob, wob, d_out, o_b, o_b, o_b, MPAD, DIM, DIM, S_LEN);
}

// Round 5
// 691.990 us; speedup vs baseline: 1.0847x; 1.0847x over previous
//
#include <hip/hip_runtime.h>

#define DIM 1536
#define NH 12
#define HD 128
#define S_LEN 5400
#define SPAD 5440      // 85*64  (kv tiles)
#define MPAD 5504      // 43*128 (GEMM M tiles / flash q tiles)
#define NQKV 4608
#define EPS_NORM 1e-6f

typedef __bf16 bf16_t;
typedef __bf16 bf16x8 __attribute__((ext_vector_type(8)));
typedef __bf16 bf16x4 __attribute__((ext_vector_type(4)));
typedef float  f32x4  __attribute__((ext_vector_type(4)));
typedef float  f32x16 __attribute__((ext_vector_type(16)));

// async global->LDS, 16B per lane; LDS dest is wave-uniform base + lane*16
#define GLOAD_LDS16(gp, lp) __builtin_amdgcn_global_load_lds( \
    (__attribute__((address_space(1))) void*)(void*)(gp),     \
    (__attribute__((address_space(3))) void*)(lp), 16, 0, 0)

// ---------------- conversion kernels ----------------

__global__ __launch_bounds__(256) void cvt_x_kernel(const float* __restrict__ x,
                                                    bf16_t* __restrict__ xb) {
  size_t base = ((size_t)blockIdx.x * 256 + threadIdx.x) * 4;
  if (base >= (size_t)MPAD * DIM) return;
  size_t row = base / DIM;
  float4 v = make_float4(0.f, 0.f, 0.f, 0.f);
  if (row < S_LEN) v = *(const float4*)&x[base];
  bf16x4 o; o[0] = (__bf16)v.x; o[1] = (__bf16)v.y; o[2] = (__bf16)v.z; o[3] = (__bf16)v.w;
  *(bf16x4*)&xb[base] = o;
}

__global__ __launch_bounds__(256) void cvt_wqkv_kernel(const float* __restrict__ qw,
                                                       const float* __restrict__ kw,
                                                       const float* __restrict__ vw,
                                                       bf16_t* __restrict__ wb) {
  size_t base = ((size_t)blockIdx.x * 256 + threadIdx.x) * 4;
  if (base >= (size_t)NQKV * DIM) return;
  int row = (int)(base / DIM);
  int col = (int)(base - (size_t)row * DIM);
  const float* src; int rr = row;
  if (rr >= 3072)      { src = vw; rr -= 3072; }
  else if (rr >= 1536) { src = kw; rr -= 1536; }
  else                 { src = qw; }
  float4 v = *(const float4*)&src[(size_t)rr * DIM + col];
  bf16x4 o; o[0] = (__bf16)v.x; o[1] = (__bf16)v.y; o[2] = (__bf16)v.z; o[3] = (__bf16)v.w;
  *(bf16x4*)&wb[base] = o;
}

__global__ __launch_bounds__(256) void cvt_wo_kernel(const float* __restrict__ w,
                                                     bf16_t* __restrict__ wb) {
  size_t base = ((size_t)blockIdx.x * 256 + threadIdx.x) * 4;
  if (base >= (size_t)DIM * DIM) return;
  float4 v = *(const float4*)&w[base];
  bf16x4 o; o[0] = (__bf16)v.x; o[1] = (__bf16)v.y; o[2] = (__bf16)v.z; o[3] = (__bf16)v.w;
  *(bf16x4*)&wb[base] = o;
}

// ---------------- GEMM: C[M,N] = A[M,K] @ B[N,K]^T + bias ----------------

template<bool OUT_BF16>
__global__ __launch_bounds__(256) void gemm_bt_kernel(
    const bf16_t* __restrict__ A, const bf16_t* __restrict__ B, void* __restrict__ C,
    const float* __restrict__ bias0, const float* __restrict__ bias1,
    const float* __restrict__ bias2, int M, int N, int K, int Mvalid) {
  __shared__ bf16_t As[128 * 32];
  __shared__ bf16_t Bs[128 * 32];
  int tid = threadIdx.x;
  int lane = tid & 63, wave = tid >> 6, quad = lane >> 4, l16 = lane & 15;
  int m0 = blockIdx.y * 128, n0 = blockIdx.x * 128;
  int wm = (wave >> 1) * 64, wn = (wave & 1) * 64;
  const bf16_t* Ab = A + (size_t)m0 * K;
  const bf16_t* Bb = B + (size_t)n0 * K;
  f32x4 acc[4][4] = {};
  for (int kt = 0; kt < K; kt += 32) {
    __syncthreads();
#pragma unroll
    for (int i = 0; i < 2; i++) {
      int eo = (i * 256 + tid) * 8;       // 128x32 tile, 8 bf16 per lane-slot
      int row = eo >> 5, col = eo & 31;
      GLOAD_LDS16(Ab + (size_t)row * K + kt + col, &As[eo]);
      GLOAD_LDS16(Bb + (size_t)row * K + kt + col, &Bs[eo]);
    }
    __syncthreads();
    bf16x8 af[4], bfr[4];
#pragma unroll
    for (int i = 0; i < 4; i++)
      af[i] = *(const bf16x8*)&As[(wm + i * 16 + l16) * 32 + quad * 8];
#pragma unroll
    for (int j = 0; j < 4; j++)
      bfr[j] = *(const bf16x8*)&Bs[(wn + j * 16 + l16) * 32 + quad * 8];
#pragma unroll
    for (int i = 0; i < 4; i++)
#pragma unroll
      for (int j = 0; j < 4; j++)
        acc[i][j] = __builtin_amdgcn_mfma_f32_16x16x32_bf16(af[i], bfr[j], acc[i][j], 0, 0, 0);
  }
  // epilogue: C/D layout col=lane&15, row=quad*4+reg  [m89-verified]
#pragma unroll
  for (int j = 0; j < 4; j++) {
    int n = n0 + wn + j * 16 + l16;
    float bias = (n < 1536) ? bias0[n] : (n < 3072) ? bias1[n - 1536] : bias2[n - 3072];
#pragma unroll
    for (int i = 0; i < 4; i++) {
#pragma unroll
      for (int r = 0; r < 4; r++) {
        int m = m0 + wm + i * 16 + quad * 4 + r;
        float v = acc[i][j][r] + bias;
        if (OUT_BF16) {
          ((bf16_t*)C)[(size_t)m * N + n] = (__bf16)v;
        } else {
          if (m < Mvalid) ((float*)C)[(size_t)m * N + n] = v;
        }
      }
    }
  }
}

// ---------------- RMSNorm + RoPE for q,k ----------------
// q additionally pre-scaled by 1/sqrt(HD) so flash logits need no scale.

__global__ __launch_bounds__(256) void rope_qk_kernel(
    const bf16_t* __restrict__ qkv, const float* __restrict__ nqw,
    const float* __restrict__ nkw, const float* __restrict__ fcos,
    const float* __restrict__ fsin, bf16_t* __restrict__ qout,
    bf16_t* __restrict__ kout) {
  int s = blockIdx.x;              // 0..MPAD-1
  int tid = threadIdx.x;
  bool valid = s < S_LEN;
  int f = s / 900, hh = (s / 30) % 30, ww = s % 30;
  __shared__ float red[4];
  for (int which = 0; which < 2; which++) {
    const bf16_t* src = qkv + (size_t)s * NQKV + which * DIM;
    const float* nw = which ? nkw : nqw;
    bf16_t* dst = (which ? kout : qout) + (size_t)s * DIM;
    float osc = which ? 1.0f : 0.08838834764831845f;   // 1/sqrt(128) folded into q
    float v[6]; float ss = 0.f;
#pragma unroll
    for (int i = 0; i < 6; i++) {
      v[i] = valid ? (float)src[tid * 6 + i] : 0.f;
      ss += v[i] * v[i];
    }
#pragma unroll
    for (int off = 32; off >= 1; off >>= 1) ss += __shfl_down(ss, off);
    if ((tid & 63) == 0) red[tid >> 6] = ss;
    __syncthreads();
    float tot = red[0] + red[1] + red[2] + red[3];
    float rn = rsqrtf(tot * (1.f / DIM) + EPS_NORM);
    __syncthreads();   // protect red[] before next `which` iteration
#pragma unroll
    for (int i = 0; i < 3; i++) {
      int e0 = tid * 6 + 2 * i;
      int p = e0 >> 1;             // pair index; cc = p&63
      int cc = p & 63;
      int pos = (cc < 22) ? f : (cc < 43) ? hh : ww;  // split [22,21,21]
      float c = fcos[pos * 64 + cc], sn = fsin[pos * 64 + cc];
      float xr = v[2 * i] * rn * nw[e0];
      float xi = v[2 * i + 1] * rn * nw[e0 + 1];
      dst[e0]     = (__bf16)((xr * c - xi * sn) * osc);
      dst[e0 + 1] = (__bf16)((xr * sn + xi * c) * osc);
    }
  }
}

// ---------------- V transpose: qkv v-part -> vt[h][d][s] ----------------

__global__ __launch_bounds__(256) void v_transpose_kernel(const bf16_t* __restrict__ qkv,
                                                          bf16_t* __restrict__ vt) {
  __shared__ bf16_t tile[64][136];   // +8 pad
  int h = blockIdx.y, s0 = blockIdx.x * 64, tid = threadIdx.x;
#pragma unroll
  for (int it = 0; it < 4; it++) {
    int eo = (it * 256 + tid) * 8;   // 64x128 elements
    int row = eo >> 7, col = eo & 127;
    int s = s0 + row;
    bf16x8 val = {};
    if (s < S_LEN) val = *(const bf16x8*)&qkv[(size_t)s * NQKV + 3072 + h * HD + col];
    *(bf16x8*)&tile[row][col] = val;
  }
  __syncthreads();
  int d = tid & 127, j0 = (tid >> 7) * 32;
  bf16x8 outv[4];
#pragma unroll
  for (int b = 0; b < 4; b++)
#pragma unroll
    for (int j = 0; j < 8; j++) outv[b][j] = tile[j0 + b * 8 + j][d];
  size_t base = ((size_t)h * HD + d) * SPAD + s0 + j0;
#pragma unroll
  for (int b = 0; b < 4; b++) *(bf16x8*)&vt[base + b * 8] = outv[b];
}

// ---------------- flash attention (S^T = K Q^T, 32x32x16 MFMA) ----------------
// grid (43 q-tiles of 128, 12 heads); 256 threads = 4 waves, wave owns 32 q.
// One b128 LDS read per 32768-FLOP MFMA (2x better than 16x16x32).
// C/D 32x32 layout: col=lane&31, row=(reg&3)+8*(reg>>2)+4*(lane>>5)  [m74/m101]
// A/B frag: row/col=lane&31, k=(lane>>5)*8+j.
// Softmax per-lane (q=lane&31): one shfl_xor(32) each for max/sum.
// P transform via per-wave swizzled LDS buffer (b64 granularity).

__global__ __launch_bounds__(256, 2) void flash_attn_kernel(
    const bf16_t* __restrict__ q, const bf16_t* __restrict__ k,
    const bf16_t* __restrict__ vt, bf16_t* __restrict__ o) {
  __shared__ bf16_t Ks[64 * 128];    // 16 KB: [kv 64][k 128], 16B chunk c at pc = c^(row&15)
  __shared__ bf16_t Vs[64 * 128];    // 16 KB: row r holds d=2r,2r+1; chunk c'=(d&1)*8+(kv>>3), pc=c'^(r&15)
  __shared__ bf16_t Pw[4][32 * 64];  // 16 KB: per-wave [q 32][kv 64], 8B chunk c8=kv>>2 at pc8=c8^(q&15)
  int head = blockIdx.y;
  int s0 = blockIdx.x * 128;
  int tid = threadIdx.x, w = tid >> 6, lane = tid & 63;
  int l31 = lane & 31, hh = lane >> 5;

  // ---- Q B-frags from global (loop-invariant, 85x reuse): B[col=q][k=16kc+8hh+j]
  bf16x8 bq[8];
  {
    const bf16_t* qp = &q[(size_t)(s0 + w * 32 + l31) * DIM + head * HD + hh * 8];
#pragma unroll
    for (int kc = 0; kc < 8; kc++) bq[kc] = *(const bf16x8*)(qp + kc * 16);
  }

  float m_i = -1e30f, l_i = 0.f;
  f32x16 oacc[4] = {};   // O^T: d = dt*32 + (r&3)+8*(r>>2)+4*hh, col q = l31

  for (int kt = 0; kt < SPAD; kt += 64) {
    __syncthreads();
    // stage K tile 64 kv x 128 k
#pragma unroll
    for (int it = 0; it < 4; it++) {
      int slot = it * 256 + tid;
      int row = slot >> 4, pc = slot & 15;
      int c = pc ^ (row & 15);
      GLOAD_LDS16(k + (size_t)(kt + row) * DIM + head * HD + c * 8, &Ks[slot * 8]);
    }
    // stage V^T tile 128 d x 64 kv (d-pair interleaved rows)
#pragma unroll
    for (int it = 0; it < 4; it++) {
      int slot = it * 256 + tid;
      int row = slot >> 4, pc = slot & 15;
      int cp = pc ^ (row & 15);
      int d = 2 * row + (cp >> 3);
      GLOAD_LDS16(vt + ((size_t)head * HD + d) * SPAD + kt + (cp & 7) * 8, &Vs[slot * 8]);
    }
    __syncthreads();

    // ---- S^T = K Q^T : 2 kv-tiles x 8 k-chunks of 32x32x16
    f32x16 sacc[2] = {};
#pragma unroll
    for (int ns = 0; ns < 2; ns++) {
      int row = ns * 32 + l31;
#pragma unroll
      for (int kc = 0; kc < 8; kc++) {
        int pc = (kc * 2 + hh) ^ (row & 15);
        bf16x8 ak = *(const bf16x8*)&Ks[row * 128 + pc * 8];
        sacc[ns] = __builtin_amdgcn_mfma_f32_32x32x16_bf16(ak, bq[kc], sacc[ns], 0, 0, 0);
      }
    }

    // ---- mask (final tile only)
    if (kt + 64 > S_LEN) {
#pragma unroll
      for (int ns = 0; ns < 2; ns++)
#pragma unroll
        for (int r = 0; r < 16; r++) {
          int kvg = kt + ns * 32 + (r & 3) + 8 * (r >> 2) + 4 * hh;
          if (kvg >= S_LEN) sacc[ns][r] = -1e30f;
        }
    }

    // ---- online softmax, per q (= per lane, replicated across hh)
    float mx = -1e30f;
#pragma unroll
    for (int ns = 0; ns < 2; ns++)
#pragma unroll
      for (int r = 0; r < 16; r++) mx = fmaxf(mx, sacc[ns][r]);
    mx = fmaxf(mx, __shfl_xor(mx, 32));
    float mn = fmaxf(m_i, mx);
    float al = __expf(m_i - mn);
    m_i = mn;
    float rs = 0.f;
#pragma unroll
    for (int ns = 0; ns < 2; ns++)
#pragma unroll
      for (int r = 0; r < 16; r++) {
        float p = __expf(sacc[ns][r] - mn);
        rs += p;
        sacc[ns][r] = p;
      }
    rs += __shfl_xor(rs, 32);
    l_i = l_i * al + rs;
#pragma unroll
    for (int dt = 0; dt < 4; dt++)
#pragma unroll
      for (int r = 0; r < 16; r++) oacc[dt][r] *= al;

    // ---- P -> per-wave LDS [q][kv] (b64 chunks, swizzled)
#pragma unroll
    for (int ns = 0; ns < 2; ns++)
#pragma unroll
      for (int t = 0; t < 4; t++) {
        bf16x4 pk;
#pragma unroll
        for (int r4 = 0; r4 < 4; r4++) pk[r4] = (__bf16)sacc[ns][t * 4 + r4];
        int c8 = ns * 8 + 2 * t + hh;          // kv chunk (ns*32 + 8t + 4hh)/4
        int pc8 = c8 ^ (l31 & 15);
        *(bf16x4*)&Pw[w][l31 * 64 + pc8 * 4] = pk;
      }

    // ---- O^T += V^T P^T : 4 d-tiles x 4 kv-chunks of 32x32x16
#pragma unroll
    for (int kvc = 0; kvc < 4; kvc++) {
      int c8a = kvc * 4 + hh * 2;
      bf16x4 plo = *(const bf16x4*)&Pw[w][l31 * 64 + ((c8a) ^ (l31 & 15)) * 4];
      bf16x4 phi = *(const bf16x4*)&Pw[w][l31 * 64 + ((c8a + 1) ^ (l31 & 15)) * 4];
      bf16x8 bp;
#pragma unroll
      for (int j = 0; j < 4; j++) { bp[j] = plo[j]; bp[j + 4] = phi[j]; }
#pragma unroll
      for (int dt = 0; dt < 4; dt++) {
        int d = dt * 32 + l31;
        int r = d >> 1;
        int cp = ((d & 1) << 3) | (kvc * 2 + hh);
        int pc = cp ^ (r & 15);
        bf16x8 av = *(const bf16x8*)&Vs[r * 128 + pc * 8];
        oacc[dt] = __builtin_amdgcn_mfma_f32_32x32x16_bf16(av, bp, oacc[dt], 0, 0, 0);
      }
    }
  }

  // ---- epilogue: O^T -> per-wave LDS transpose (2 halves of 64 d) -> global
  float inv = 1.f / l_i;
  int qr = lane >> 1, seg = lane & 1;
  int srow = s0 + w * 32 + qr;
#pragma unroll
  for (int half = 0; half < 2; half++) {
#pragma unroll
    for (int dl = 0; dl < 2; dl++) {
      int dt = half * 2 + dl;
#pragma unroll
      for (int t = 0; t < 4; t++) {
        bf16x4 v;
#pragma unroll
        for (int r4 = 0; r4 < 4; r4++) v[r4] = (__bf16)(oacc[dt][t * 4 + r4] * inv);
        int c8 = dl * 8 + 2 * t + hh;          // d chunk (dl*32 + 8t + 4hh)/4
        int pc8 = c8 ^ (l31 & 15);
        *(bf16x4*)&Pw[w][l31 * 64 + pc8 * 4] = v;
      }
    }
    // same-wave DS ordering guarantees write->read visibility
#pragma unroll
    for (int i = 0; i < 4; i++) {
      int c8 = seg * 8 + 2 * i;
      bf16x4 lo = *(const bf16x4*)&Pw[w][qr * 64 + ((c8) ^ (qr & 15)) * 4];
      bf16x4 hi = *(const bf16x4*)&Pw[w][qr * 64 + ((c8 + 1) ^ (qr & 15)) * 4];
      bf16x8 val;
#pragma unroll
      for (int j = 0; j < 4; j++) { val[j] = lo[j]; val[j + 4] = hi[j]; }
      if (srow < S_LEN)
        *(bf16x8*)&o[(size_t)srow * DIM + head * HD + half * 64 + seg * 32 + i * 8] = val;
    }
    __syncthreads();   // reuse of Pw across halves; also isolates from other waves' region? per-wave region, but cheap
  }
}

// ---------------- launch ----------------

extern "C" void kernel_launch(void* const* d_in, const int* in_sizes, int n_in,
                              void* d_out, int out_size, void* d_ws, size_t ws_size,
                              hipStream_t stream) {
  const float* x    = (const float*)d_in[0];
  const float* q_w  = (const float*)d_in[1];
  const float* q_b  = (const float*)d_in[2];
  const float* k_w  = (const float*)d_in[3];
  const float* k_b  = (const float*)d_in[4];
  const float* v_w  = (const float*)d_in[5];
  const float* v_b  = (const float*)d_in[6];
  const float* o_w  = (const float*)d_in[7];
  const float* o_b  = (const float*)d_in[8];
  const float* nqw  = (const float*)d_in[9];
  const float* nkw  = (const float*)d_in[10];
  const float* fcos = (const float*)d_in[11];
  const float* fsin = (const float*)d_in[12];

  char* ws = (char*)d_ws;
  bf16_t* xb   = (bf16_t*)(ws + 0);
  bf16_t* wqkv = (bf16_t*)(ws + 16908288);
  bf16_t* wob  = (bf16_t*)(ws + 31064064);
  bf16_t* qkv  = (bf16_t*)(ws + 35782656);
  bf16_t* qb   = (bf16_t*)(ws + 86507520);
  bf16_t* kb   = (bf16_t*)(ws + 103415808);
  bf16_t* vtb  = (bf16_t*)(ws + 0);         // alias xb (dead after GEMM1)
  bf16_t* aob  = (bf16_t*)(ws + 35782656);  // alias qkv (dead after rope+transpose)

  cvt_x_kernel<<<(MPAD * DIM / 4 + 255) / 256, 256, 0, stream>>>(x, xb);
  cvt_wqkv_kernel<<<(NQKV * DIM / 4 + 255) / 256, 256, 0, stream>>>(q_w, k_w, v_w, wqkv);
  cvt_wo_kernel<<<(DIM * DIM / 4 + 255) / 256, 256, 0, stream>>>(o_w, wob);

  gemm_bt_kernel<true><<<dim3(NQKV / 128, MPAD / 128), 256, 0, stream>>>(
      xb, wqkv, qkv, q_b, k_b, v_b, MPAD, NQKV, DIM, MPAD);

  rope_qk_kernel<<<MPAD, 256, 0, stream>>>(qkv, nqw, nkw, fcos, fsin, qb, kb);
  v_transpose_kernel<<<dim3(SPAD / 64, NH), 256, 0, stream>>>(qkv, vtb);

  flash_attn_kernel<<<dim3(MPAD / 128, NH), 256, 0, stream>>>(qb, kb, vtb, aob);

  gemm_bt_kernel<false><<<dim3(DIM / 128, MPAD / 128), 256, 0, stream>>>(
      aob, wob, d_out, o_b, o_b, o_b, MPAD, DIM, DIM, S_LEN);
}